// Round 19
// baseline (113.781 us; speedup 1.0000x reference)
//
#include <hip/hip_runtime.h>
#include <stdint.h>

#define H 8
#define DH 96
#define L 2048
#define NB 2
#define D 768

typedef unsigned short u16;
typedef unsigned int u32;
typedef __attribute__((ext_vector_type(4))) __bf16 bf16x4;
typedef __attribute__((ext_vector_type(8))) __bf16 bf16x8;
typedef __attribute__((ext_vector_type(4))) float f32x4;
typedef __attribute__((ext_vector_type(16))) float f32x16;
typedef __attribute__((ext_vector_type(4))) u32 u32x4;
typedef __attribute__((ext_vector_type(2))) u32 u32x2;
typedef __attribute__((ext_vector_type(4))) u16 u16x4;

// softmax scale folded with log2(e): 96^-0.5 * 1.4426950408889634
#define QSCALE 0.14724444f

static __device__ __forceinline__ u16 f2bf(float f) {
  union { __bf16 h; u16 u; } v;
  v.h = (__bf16)f;
  return v.u;
}

static __device__ __forceinline__ bf16x8 cvt8r(f32x4 a, f32x4 b) {
  bf16x8 r;
  r[0] = (__bf16)a[0]; r[1] = (__bf16)a[1]; r[2] = (__bf16)a[2]; r[3] = (__bf16)a[3];
  r[4] = (__bf16)b[0]; r[5] = (__bf16)b[1]; r[6] = (__bf16)b[2]; r[7] = (__bf16)b[3];
  return r;
}

// ---------------------------------------------------------------------------
// Fused QKV projection + RoPE (z=0: Q, z=1: K, z=2: V->V^T)  — frozen r15
// ---------------------------------------------------------------------------
__global__ __launch_bounds__(256, 3)
void proj_qkv(const float* __restrict__ Qin, const float* __restrict__ Kin,
              const float* __restrict__ Vin,
              const float* __restrict__ Wq, const float* __restrict__ Wk,
              const float* __restrict__ Wv,
              const float* __restrict__ cq, const float* __restrict__ ck,
              u16* __restrict__ qo, u16* __restrict__ ko, u16* __restrict__ vo)
{
  __shared__ u16 a_lds[2][64 * 40];
  __shared__ u16 b_lds[2][192 * 40];
  const int tid = threadIdx.x;
  const int lane = tid & 63;
  const int w = tid >> 6;
  const int wr = w >> 1, wc = w & 1;
  const int fr = lane & 15;
  const int hi = lane >> 4;

  const int f = blockIdx.x;
  const int xcd = f & 7;
  const int g = f >> 3;          // 0..95
  const int bx = g & 3;
  const int h2 = g >> 2;         // 0..23
  const int byp = h2 & 7;
  const int z = h2 >> 3;
  const int by = xcd + 8 * byp;  // 0..63
  const int row0 = by * 64;
  const int col0 = bx * 192;

  const float* A = (z == 0) ? Qin : ((z == 1) ? Kin : Vin);
  const float* W = (z == 0) ? Wq : ((z == 1) ? Wk : Wv);

  const int arow = tid >> 2;
  const int acol = (tid & 3) * 8;
  const float* pA = A + (size_t)(row0 + arow) * D + acol;
  const float* pB0 = W + (size_t)(col0 + arow) * D + acol;
  const float* pB1 = pB0 + (size_t)64 * D;
  const float* pB2 = pB0 + (size_t)128 * D;

  f32x4 acc[2][6] = {};
  f32x4 Ra[2], Rb[6];

  auto issue = [&](int k) {
    Ra[0] = *(const f32x4*)(pA + k);
    Ra[1] = *(const f32x4*)(pA + k + 4);
    Rb[0] = *(const f32x4*)(pB0 + k);
    Rb[1] = *(const f32x4*)(pB0 + k + 4);
    Rb[2] = *(const f32x4*)(pB1 + k);
    Rb[3] = *(const f32x4*)(pB1 + k + 4);
    Rb[4] = *(const f32x4*)(pB2 + k);
    Rb[5] = *(const f32x4*)(pB2 + k + 4);
  };
  auto stage = [&](int bi) {
    *(bf16x8*)(&a_lds[bi][arow * 40 + acol]) = cvt8r(Ra[0], Ra[1]);
    *(bf16x8*)(&b_lds[bi][arow * 40 + acol]) = cvt8r(Rb[0], Rb[1]);
    *(bf16x8*)(&b_lds[bi][(arow + 64) * 40 + acol]) = cvt8r(Rb[2], Rb[3]);
    *(bf16x8*)(&b_lds[bi][(arow + 128) * 40 + acol]) = cvt8r(Rb[4], Rb[5]);
  };
  auto compute = [&](int bi) {
    bf16x8 af[2], bf[6];
#pragma unroll
    for (int m = 0; m < 2; m++)
      af[m] = *(const bf16x8*)(&a_lds[bi][(wr * 32 + m * 16 + fr) * 40 + hi * 8]);
#pragma unroll
    for (int n = 0; n < 6; n++)
      bf[n] = *(const bf16x8*)(&b_lds[bi][(wc * 96 + n * 16 + fr) * 40 + hi * 8]);
#pragma unroll
    for (int m = 0; m < 2; m++)
#pragma unroll
      for (int n = 0; n < 6; n++)
        acc[m][n] = __builtin_amdgcn_mfma_f32_16x16x32_bf16(af[m], bf[n], acc[m][n], 0, 0, 0);
  };

  issue(0);
  stage(0);
  __syncthreads();

  int cur = 0;
#pragma unroll 1
  for (int t = 0; t < 24; t++) {
    if (t + 1 < 24) issue((t + 1) * 32);
    compute(cur);
    if (t + 1 < 24) stage(cur ^ 1);
    __syncthreads();
    cur ^= 1;
  }

  const int hh = (col0 + wc * 96) / DH;
  if (z == 2) {
#pragma unroll
    for (int m = 0; m < 2; m++) {
      int rbase = row0 + wr * 32 + m * 16 + hi * 4;
#pragma unroll
      for (int n = 0; n < 6; n++) {
        int dd = n * 16 + fr;
#pragma unroll
        for (int r = 0; r < 4; r++) {
          int row = rbase + r;
          int b = row >> 11, l = row & (L - 1);
          vo[((size_t)((b * H + hh) * DH + dd)) * L + l] = f2bf(acc[m][n][r]);
        }
      }
    }
  } else {
    const float* coords = (z == 0) ? cq : ck;
    u16* outp = (z == 0) ? qo : ko;
    const float postscale = (z == 0) ? QSCALE : 1.0f;
    const float invf = exp2f(-(float)fr * 0.83048202372184058f);
#pragma unroll
    for (int m = 0; m < 2; m++) {
      int rbase = row0 + wr * 32 + m * 16 + hi * 4;
#pragma unroll
      for (int np = 0; np < 3; np++) {
        int n1 = np * 2;
        int dd1 = n1 * 16 + fr;
#pragma unroll
        for (int r = 0; r < 4; r++) {
          int row = rbase + r;
          int b = row >> 11, l = row & (L - 1);
          float coord = coords[((size_t)(b * L + l)) * 3 + np];
          float ang = coord * invf;
          float sn = __sinf(ang), cs = __cosf(ang);
          float x1 = acc[m][n1][r], x2 = acc[m][n1 + 1][r];
          size_t base = ((size_t)((b * H + hh) * L + l)) * DH;
          outp[base + dd1] = f2bf((x1 * cs - x2 * sn) * postscale);
          outp[base + dd1 + 16] = f2bf((x1 * sn + x2 * cs) * postscale);
        }
      }
    }
  }
}

// ---------------------------------------------------------------------------
// Flash attention: 32x32x16 MFMA, q=64 per wave (2 q-groups), 2-wave k-split
// blocks (128 thr). Per wave per tile: 12 b128 reads feed 24 MFMA-32.
// K staged via global_load_lds lane-linear (KSTR=96, natural d order — QK
// needs no perm since both operands share the slot->k map). V staged with
// the tau middle-chunk-swap matching P's register k-order. Per-lane 2 q-rows
// with per-group m/l + defer-max; epilogue k-merge via LDS scratch.
// r18 BUGFIX: kdma chunk loop c<6 (12 chunks total across 2 waves), was c<12
// -> double coverage overflowing into the compute buffer.
// ---------------------------------------------------------------------------
#define KSTR 96
#define VSTR 72
#define NT   (L / 64)
__global__ __launch_bounds__(128, 1)
void attn_fwd(const u16* __restrict__ q_ws, const u16* __restrict__ k_ws,
              const u16* __restrict__ vt_ws, u16* __restrict__ ao)
{
  __shared__ __attribute__((aligned(16))) u16 k_lds[2][64 * KSTR];   // 24.5 KB
  __shared__ __attribute__((aligned(16))) u16 vt_lds[2][96 * VSTR];  // 27.6 KB
  const int tid = threadIdx.x;   // 0..127
  const int lane = tid & 63;
  const int w = tid >> 6;        // 0..1 = k-half

  // swizzle: q-tiles of one bh share f%8 -> same XCD (K/V L2-resident)
  const int f = blockIdx.x;
  const int xr = f & 7;
  const int g = f >> 3;          // 0..63
  const int qx = g & 31;
  const int bh = xr + 8 * (g >> 5);
  const int q0 = qx * 64;

  const int qlo = lane & 31;
  const int hi32 = lane >> 5;
  const int kk0 = w * 32;

  const u16* kbase = k_ws + (size_t)bh * L * DH;
  const u16* vtbase = vt_ws + (size_t)bh * DH * L;

  const int perm[4] = {0, 2, 1, 3};

  // V staging: 6 x u32x4 loads -> 12 perm'd b64 writes per thread
  int vg_off[6], vl0[6], vl1[6];
#pragma unroll
  for (int it = 0; it < 6; it++) {
    int ch = tid + it * 128;              // 0..767
    int vrow = ch >> 3, vq = (ch & 7) * 2;
    vg_off[it] = vrow * L + vq * 4;
    vl0[it] = vrow * VSTR + (vq >> 2) * 16 + perm[vq & 3] * 4;
    vl1[it] = vrow * VSTR + (vq >> 2) * 16 + perm[(vq + 1) & 3] * 4;
  }

  // K DMA: tile = 6144 u16 = 12 chunks of 512; 6 chunks per wave (blk=c*2+w)
  auto kdma = [&](int t, int bi) {
#pragma unroll
    for (int c = 0; c < 6; c++) {
      const int blk = c * 2 + w;   // 0..11
      const u16* gp = kbase + (size_t)t * 64 * DH + ((size_t)blk * 64 + lane) * 8;
      u16* lp = &k_lds[bi][(size_t)blk * 512];
      __builtin_amdgcn_global_load_lds(
          (const __attribute__((address_space(1))) u32*)gp,
          (__attribute__((address_space(3))) u32*)lp, 16, 0, 0);
    }
  };

  // Q B-frags (natural d order): 6 slices x 2 groups
  bf16x8 qf[2][6];
  {
    const u16* qb0 = q_ws + ((size_t)bh * L + q0 + qlo) * DH;
    const u16* qb1 = qb0 + (size_t)32 * DH;
#pragma unroll
    for (int s = 0; s < 6; s++) {
      qf[0][s] = *(const bf16x8*)(qb0 + s * 16 + hi32 * 8);
      qf[1][s] = *(const bf16x8*)(qb1 + s * 16 + hi32 * 8);
    }
  }

  f32x16 oA[3] = {}, oB[3] = {};
  float mA = -1e30f, lA = 0.f, mB = -1e30f, lB = 0.f;

  u32x4 vreg[6];
  auto vissue = [&](int t) {
    const u16* vb = vtbase + t * 64;
#pragma unroll
    for (int it = 0; it < 6; it++)
      vreg[it] = *(const u32x4*)(vb + vg_off[it]);
  };
  auto vwrite = [&](int bi) {
#pragma unroll
    for (int it = 0; it < 6; it++) {
      u32x2 lo = { vreg[it][0], vreg[it][1] };
      u32x2 hi2 = { vreg[it][2], vreg[it][3] };
      *(u32x2*)(&vt_lds[bi][vl0[it]]) = lo;
      *(u32x2*)(&vt_lds[bi][vl1[it]]) = hi2;
    }
  };

  // prologue: tile 0 -> buf 0
  kdma(0, 0);
  vissue(0);
  vwrite(0);
  __syncthreads();

  int cur = 0;
  for (int t = 0; t < NT; t++) {
    if (t + 1 < NT) {
      kdma(t + 1, cur ^ 1);   // DMA direct into next buffer
      vissue(t + 1);
    }

    // QK: S^T[k][q] both groups; kfrag shared
    f32x16 sA = {}, sB = {};
#pragma unroll
    for (int s = 0; s < 6; s++) {
      bf16x8 kfrag = *(const bf16x8*)(
          &k_lds[cur][(kk0 + qlo) * KSTR + s * 16 + hi32 * 8]);
      sA = __builtin_amdgcn_mfma_f32_32x32x16_bf16(kfrag, qf[0][s], sA, 0, 0, 0);
      sB = __builtin_amdgcn_mfma_f32_32x32x16_bf16(kfrag, qf[1][s], sB, 0, 0, 0);
    }

    // group A softmax (defer-max)
    bf16x8 ptA[2], ptB[2];
    {
      float a0 = fmaxf(fmaxf(sA[0], sA[1]), sA[2]);
      float a1 = fmaxf(fmaxf(sA[3], sA[4]), sA[5]);
      float a2 = fmaxf(fmaxf(sA[6], sA[7]), sA[8]);
      float a3 = fmaxf(fmaxf(sA[9], sA[10]), sA[11]);
      float a4 = fmaxf(fmaxf(sA[12], sA[13]), sA[14]);
      float pmax = fmaxf(fmaxf(fmaxf(a0, a1), a2), fmaxf(fmaxf(a3, a4), sA[15]));
      if (!__all(pmax - mA <= 8.0f)) {
        float mx = fmaxf(pmax, __shfl_xor(pmax, 32));
        float mn = fmaxf(mA, mx);
        float alpha = exp2f(mA - mn);
        mA = mn;
        lA *= alpha;
#pragma unroll
        for (int db = 0; db < 3; db++)
#pragma unroll
          for (int r = 0; r < 16; r++)
            oA[db][r] *= alpha;
      }
      float p[16];
      float rs = 0.f;
#pragma unroll
      for (int r = 0; r < 16; r++) { p[r] = exp2f(sA[r] - mA); rs += p[r]; }
      lA += rs;
#pragma unroll
      for (int s = 0; s < 2; s++)
#pragma unroll
        for (int j = 0; j < 8; j++)
          ptA[s][j] = (__bf16)p[s * 8 + j];
    }
    // group B softmax
    {
      float a0 = fmaxf(fmaxf(sB[0], sB[1]), sB[2]);
      float a1 = fmaxf(fmaxf(sB[3], sB[4]), sB[5]);
      float a2 = fmaxf(fmaxf(sB[6], sB[7]), sB[8]);
      float a3 = fmaxf(fmaxf(sB[9], sB[10]), sB[11]);
      float a4 = fmaxf(fmaxf(sB[12], sB[13]), sB[14]);
      float pmax = fmaxf(fmaxf(fmaxf(a0, a1), a2), fmaxf(fmaxf(a3, a4), sB[15]));
      if (!__all(pmax - mB <= 8.0f)) {
        float mx = fmaxf(pmax, __shfl_xor(pmax, 32));
        float mn = fmaxf(mB, mx);
        float alpha = exp2f(mB - mn);
        mB = mn;
        lB *= alpha;
#pragma unroll
        for (int db = 0; db < 3; db++)
#pragma unroll
          for (int r = 0; r < 16; r++)
            oB[db][r] *= alpha;
      }
      float p[16];
      float rs = 0.f;
#pragma unroll
      for (int r = 0; r < 16; r++) { p[r] = exp2f(sB[r] - mB); rs += p[r]; }
      lB += rs;
#pragma unroll
      for (int s = 0; s < 2; s++)
#pragma unroll
        for (int j = 0; j < 8; j++)
          ptB[s][j] = (__bf16)p[s * 8 + j];
    }

    // PV: vfrag shared by both groups
#pragma unroll
    for (int s = 0; s < 2; s++)
#pragma unroll
      for (int db = 0; db < 3; db++) {
        bf16x8 vfrag = *(const bf16x8*)(
            &vt_lds[cur][(db * 32 + qlo) * VSTR + kk0 + s * 16 + hi32 * 8]);
        oA[db] = __builtin_amdgcn_mfma_f32_32x32x16_bf16(vfrag, ptA[s], oA[db], 0, 0, 0);
        oB[db] = __builtin_amdgcn_mfma_f32_32x32x16_bf16(vfrag, ptB[s], oB[db], 0, 0, 0);
      }

    if (t + 1 < NT) {
      vwrite(cur ^ 1);        // buf last read at t-1 (ordered by prev barrier)
      __syncthreads();        // drains K-DMA + V writes for tile t+1
      cur ^= 1;
    }
  }

  // per-row l across hi32 pair
  float lAw = lA + __shfl_xor(lA, 32);
  float lBw = lB + __shfl_xor(lB, 32);

  __syncthreads();  // all waves done reading LDS buffers

  // k-split merge: wave 1 publishes, wave 0 merges + stores.
  float* xa = (float*)&k_lds[0][0];    // group A scratch
  float* xb = (float*)&vt_lds[0][0];   // group B scratch
  const int base = lane * 52;
  if (w == 1) {
#pragma unroll
    for (int db = 0; db < 3; db++)
#pragma unroll
      for (int rg = 0; rg < 4; rg++) {
        f32x4 va = { oA[db][rg * 4], oA[db][rg * 4 + 1],
                     oA[db][rg * 4 + 2], oA[db][rg * 4 + 3] };
        *(f32x4*)&xa[base + db * 16 + rg * 4] = va;
        f32x4 vb = { oB[db][rg * 4], oB[db][rg * 4 + 1],
                     oB[db][rg * 4 + 2], oB[db][rg * 4 + 3] };
        *(f32x4*)&xb[base + db * 16 + rg * 4] = vb;
      }
    xa[base + 48] = mA; xa[base + 49] = lAw;
    xb[base + 48] = mB; xb[base + 49] = lBw;
  }
  __syncthreads();
  if (w == 0) {
    const int b = bh >> 3, hh = bh & 7;
    // group A (rows q0+qlo)
    {
      float m1 = xa[base + 48], l1 = xa[base + 49];
      float ms = fmaxf(mA, m1);
      float c0 = exp2f(mA - ms), c1 = exp2f(m1 - ms);
      float inv = 1.f / (lAw * c0 + l1 * c1);
      u16* aop = ao + ((size_t)(b * L + q0 + qlo)) * D + hh * DH;
#pragma unroll
      for (int db = 0; db < 3; db++)
#pragma unroll
        for (int rg = 0; rg < 4; rg++) {
          f32x4 op = *(const f32x4*)&xa[base + db * 16 + rg * 4];
          u16x4 pk;
#pragma unroll
          for (int r4 = 0; r4 < 4; r4++)
            pk[r4] = f2bf((oA[db][rg * 4 + r4] * c0 + op[r4] * c1) * inv);
          *(u16x4*)(aop + db * 32 + rg * 8 + hi32 * 4) = pk;
        }
    }
    // group B (rows q0+32+qlo)
    {
      float m1 = xb[base + 48], l1 = xb[base + 49];
      float ms = fmaxf(mB, m1);
      float c0 = exp2f(mB - ms), c1 = exp2f(m1 - ms);
      float inv = 1.f / (lBw * c0 + l1 * c1);
      u16* aop = ao + ((size_t)(b * L + q0 + 32 + qlo)) * D + hh * DH;
#pragma unroll
      for (int db = 0; db < 3; db++)
#pragma unroll
        for (int rg = 0; rg < 4; rg++) {
          f32x4 op = *(const f32x4*)&xb[base + db * 16 + rg * 4];
          u16x4 pk;
#pragma unroll
          for (int r4 = 0; r4 < 4; r4++)
            pk[r4] = f2bf((oB[db][rg * 4 + r4] * c0 + op[r4] * c1) * inv);
          *(u16x4*)(aop + db * 32 + rg * 8 + hi32 * 4) = pk;
        }
    }
  }
}

// ---------------------------------------------------------------------------
// Output projection: out = AO @ Wo^T; 64x64 tiles, XCD swizzle, 2-deep
// prefetch + dbuf LDS; (256,3): 768 blocks = 3/CU one round.  (frozen)
// ---------------------------------------------------------------------------
__global__ __launch_bounds__(256, 3)
void gemm_out(const u16* __restrict__ A, const float* __restrict__ W,
              float* __restrict__ out)
{
  __shared__ u16 a_lds[2][64 * 40];
  __shared__ u16 b_lds[2][64 * 40];
  const int tid = threadIdx.x;
  const int lane = tid & 63;
  const int w = tid >> 6;
  const int wr = w >> 1, wc = w & 1;

  const int f = blockIdx.x;
  const int xr = f & 7;
  const int g = f >> 3;          // 0..95
  const int bx = g % 12;
  const int wq = g / 12;         // 0..7
  const int by = xr + 8 * wq;    // 0..63
  const int row0 = by * 64;
  const int col0 = bx * 64;

  f32x4 acc[2][2] = {};
  const int srow = tid >> 2;
  const int scol = (tid & 3) * 8;
  const u16* pA = A + (size_t)(row0 + srow) * D + scol;
  const float* pW = W + (size_t)(col0 + srow) * D + scol;
  const int fr = lane & 15;
  const int fk = (lane >> 4) * 8;

  auto issueG = [&](int k, u32x4* ra, f32x4* rb) {
    ra[0] = *(const u32x4*)(pA + k);
    rb[0] = *(const f32x4*)(pW + k);
    rb[1] = *(const f32x4*)(pW + k + 4);
  };
  auto writeG = [&](int bi, const u32x4* ra, const f32x4* rb) {
    *(u32x4*)(&a_lds[bi][srow * 40 + scol]) = ra[0];
    *(bf16x8*)(&b_lds[bi][srow * 40 + scol]) = cvt8r(rb[0], rb[1]);
  };
  auto computeG = [&](int bi) {
    bf16x8 af[2], bfr[2];
#pragma unroll
    for (int m = 0; m < 2; m++)
      af[m] = *(const bf16x8*)(&a_lds[bi][(wr * 32 + m * 16 + fr) * 40 + fk]);
#pragma unroll
    for (int n = 0; n < 2; n++)
      bfr[n] = *(const bf16x8*)(&b_lds[bi][(wc * 32 + n * 16 + fr) * 40 + fk]);
#pragma unroll
    for (int m = 0; m < 2; m++)
#pragma unroll
      for (int n = 0; n < 2; n++)
        acc[m][n] = __builtin_amdgcn_mfma_f32_16x16x32_bf16(af[m], bfr[n], acc[m][n], 0, 0, 0);
  };

  u32x4 raA[1], raB[1];
  f32x4 rbA[2], rbB[2];
  issueG(0, raB, rbB);
  writeG(0, raB, rbB);
  issueG(32, raA, rbA);
  __syncthreads();

  for (int k0 = 0; k0 < D; k0 += 64) {
    if (k0 + 64 < D) issueG(k0 + 64, raB, rbB);
    computeG(0);
    writeG(1, raA, rbA);
    __syncthreads();
    if (k0 + 96 < D) issueG(k0 + 96, raA, rbA);
    computeG(1);
    if (k0 + 64 < D) writeG(0, raB, rbB);
    __syncthreads();
  }

#pragma unroll
  for (int m = 0; m < 2; m++) {
    int rbase = row0 + wr * 32 + m * 16 + (lane >> 4) * 4;
#pragma unroll
    for (int n = 0; n < 2; n++) {
      int c = col0 + wc * 32 + n * 16 + fr;
#pragma unroll
      for (int r = 0; r < 4; r++)
        out[(size_t)(rbase + r) * D + c] = acc[m][n][r];
    }
  }
}

extern "C" void kernel_launch(void* const* d_in, const int* in_sizes, int n_in,
                              void* d_out, int out_size, void* d_ws, size_t ws_size,
                              hipStream_t stream) {
  (void)in_sizes; (void)n_in; (void)out_size;
  const float* Qin = (const float*)d_in[0];
  const float* Kin = (const float*)d_in[1];
  const float* Vin = (const float*)d_in[2];
  const float* cq  = (const float*)d_in[3];
  const float* ck  = (const float*)d_in[4];
  const float* Wq  = (const float*)d_in[5];
  const float* Wk  = (const float*)d_in[6];
  const float* Wv  = (const float*)d_in[7];
  const float* Wo  = (const float*)d_in[8];
  float* out = (float*)d_out;

  const size_t per = (size_t)NB * H * L * DH;  // 3,145,728 elems
  if (ws_size < 4 * per * sizeof(u16)) return;

  u16* q_ws  = (u16*)d_ws;
  u16* k_ws  = q_ws + per;
  u16* vt_ws = k_ws + per;
  u16* ao_ws = vt_ws + per;

  proj_qkv<<<dim3(768), dim3(256), 0, stream>>>(
      Qin, Kin, Vin, Wq, Wk, Wv, cq, ck, q_ws, k_ws, vt_ws);
  attn_fwd<<<dim3(32 * NB * H), dim3(128), 0, stream>>>(q_ws, k_ws, vt_ws, ao_ws);
  gemm_out<<<dim3(12 * 64), dim3(256), 0, stream>>>(ao_ws, Wo, out);
}

// Round 20
// 98.159 us; speedup vs baseline: 1.1591x; 1.1591x over previous
//
#include <hip/hip_runtime.h>
#include <stdint.h>

#define H 8
#define DH 96
#define L 2048
#define NB 2
#define D 768

typedef unsigned short u16;
typedef unsigned int u32;
typedef __attribute__((ext_vector_type(4))) __bf16 bf16x4;
typedef __attribute__((ext_vector_type(8))) __bf16 bf16x8;
typedef __attribute__((ext_vector_type(4))) float f32x4;
typedef __attribute__((ext_vector_type(16))) float f32x16;
typedef __attribute__((ext_vector_type(4))) u32 u32x4;
typedef __attribute__((ext_vector_type(2))) u32 u32x2;
typedef __attribute__((ext_vector_type(4))) u16 u16x4;

// softmax scale folded with log2(e): 96^-0.5 * 1.4426950408889634
#define QSCALE 0.14724444f

static __device__ __forceinline__ u16 f2bf(float f) {
  union { __bf16 h; u16 u; } v;
  v.h = (__bf16)f;
  return v.u;
}

static __device__ __forceinline__ bf16x8 cvt8r(f32x4 a, f32x4 b) {
  bf16x8 r;
  r[0] = (__bf16)a[0]; r[1] = (__bf16)a[1]; r[2] = (__bf16)a[2]; r[3] = (__bf16)a[3];
  r[4] = (__bf16)b[0]; r[5] = (__bf16)b[1]; r[6] = (__bf16)b[2]; r[7] = (__bf16)b[3];
  return r;
}

// raw barrier: order LDS ops (lgkmcnt) but leave global loads IN FLIGHT
// (compiler's __syncthreads would force vmcnt(0), draining our prefetch).
static __device__ __forceinline__ void bar_lds() {
  asm volatile("s_waitcnt lgkmcnt(0)" ::: "memory");
  __builtin_amdgcn_s_barrier();
}

// ---------------------------------------------------------------------------
// Fused QKV projection + RoPE (z=0: Q, z=1: K, z=2: V->V^T)
// r15 geometry (768 blocks = 3/CU; BM=64 x BN=192; wave-tile 32x96) +
// 2-deep S/T register prefetch + raw lgkmcnt-only barriers: tile t's loads
// issue at step t-2 and their vmcnt wait lands at the cvt in stage (step
// t-1) — a full block-step of slack, not drained by the barrier.
// ---------------------------------------------------------------------------
__global__ __launch_bounds__(256, 3)
void proj_qkv(const float* __restrict__ Qin, const float* __restrict__ Kin,
              const float* __restrict__ Vin,
              const float* __restrict__ Wq, const float* __restrict__ Wk,
              const float* __restrict__ Wv,
              const float* __restrict__ cq, const float* __restrict__ ck,
              u16* __restrict__ qo, u16* __restrict__ ko, u16* __restrict__ vo)
{
  __shared__ u16 a_lds[2][64 * 40];
  __shared__ u16 b_lds[2][192 * 40];
  const int tid = threadIdx.x;
  const int lane = tid & 63;
  const int w = tid >> 6;
  const int wr = w >> 1, wc = w & 1;
  const int fr = lane & 15;
  const int hi = lane >> 4;

  const int f = blockIdx.x;
  const int xcd = f & 7;
  const int g = f >> 3;          // 0..95
  const int bx = g & 3;
  const int h2 = g >> 2;         // 0..23
  const int byp = h2 & 7;
  const int z = h2 >> 3;
  const int by = xcd + 8 * byp;  // 0..63
  const int row0 = by * 64;
  const int col0 = bx * 192;

  const float* A = (z == 0) ? Qin : ((z == 1) ? Kin : Vin);
  const float* W = (z == 0) ? Wq : ((z == 1) ? Wk : Wv);

  const int arow = tid >> 2;
  const int acol = (tid & 3) * 8;
  const float* pA = A + (size_t)(row0 + arow) * D + acol;
  const float* pB0 = W + (size_t)(col0 + arow) * D + acol;
  const float* pB1 = pB0 + (size_t)64 * D;
  const float* pB2 = pB0 + (size_t)128 * D;

  f32x4 acc[2][6] = {};
  f32x4 Sa[2], Sb[6], Ta[2], Tb[6];

  auto issueP = [&](int k, f32x4* ra, f32x4* rb) {
    ra[0] = *(const f32x4*)(pA + k);
    ra[1] = *(const f32x4*)(pA + k + 4);
    rb[0] = *(const f32x4*)(pB0 + k);
    rb[1] = *(const f32x4*)(pB0 + k + 4);
    rb[2] = *(const f32x4*)(pB1 + k);
    rb[3] = *(const f32x4*)(pB1 + k + 4);
    rb[4] = *(const f32x4*)(pB2 + k);
    rb[5] = *(const f32x4*)(pB2 + k + 4);
  };
  auto stageP = [&](int bi, const f32x4* ra, const f32x4* rb) {
    *(bf16x8*)(&a_lds[bi][arow * 40 + acol]) = cvt8r(ra[0], ra[1]);
    *(bf16x8*)(&b_lds[bi][arow * 40 + acol]) = cvt8r(rb[0], rb[1]);
    *(bf16x8*)(&b_lds[bi][(arow + 64) * 40 + acol]) = cvt8r(rb[2], rb[3]);
    *(bf16x8*)(&b_lds[bi][(arow + 128) * 40 + acol]) = cvt8r(rb[4], rb[5]);
  };
  auto compute = [&](int bi) {
    bf16x8 af[2], bf[6];
#pragma unroll
    for (int m = 0; m < 2; m++)
      af[m] = *(const bf16x8*)(&a_lds[bi][(wr * 32 + m * 16 + fr) * 40 + hi * 8]);
#pragma unroll
    for (int n = 0; n < 6; n++)
      bf[n] = *(const bf16x8*)(&b_lds[bi][(wc * 96 + n * 16 + fr) * 40 + hi * 8]);
#pragma unroll
    for (int m = 0; m < 2; m++)
#pragma unroll
      for (int n = 0; n < 6; n++)
        acc[m][n] = __builtin_amdgcn_mfma_f32_16x16x32_bf16(af[m], bf[n], acc[m][n], 0, 0, 0);
  };

  // prologue: tile0->S->buf0 (cold drain once); tile1->T
  issueP(0, Sa, Sb);
  stageP(0, Sa, Sb);
  issueP(32, Ta, Tb);
  bar_lds();

  // iter tt: even step computes tile 2tt (buf0), odd computes 2tt+1 (buf1).
  // issue tile t+2 at top of step t; stage tile t+1 (issued 1 full step ago).
#pragma unroll 1
  for (int tt = 0; tt < 12; tt++) {
    const int k2 = tt * 64;
    if (k2 + 64 < D) issueP(k2 + 64, Sa, Sb);   // tile 2tt+2
    compute(0);
    stageP(1, Ta, Tb);                          // tile 2tt+1
    bar_lds();
    if (k2 + 96 < D) issueP(k2 + 96, Ta, Tb);   // tile 2tt+3
    compute(1);
    if (k2 + 64 < D) stageP(0, Sa, Sb);         // tile 2tt+2
    bar_lds();
  }

  const int hh = (col0 + wc * 96) / DH;
  if (z == 2) {
#pragma unroll
    for (int m = 0; m < 2; m++) {
      int rbase = row0 + wr * 32 + m * 16 + hi * 4;
#pragma unroll
      for (int n = 0; n < 6; n++) {
        int dd = n * 16 + fr;
#pragma unroll
        for (int r = 0; r < 4; r++) {
          int row = rbase + r;
          int b = row >> 11, l = row & (L - 1);
          vo[((size_t)((b * H + hh) * DH + dd)) * L + l] = f2bf(acc[m][n][r]);
        }
      }
    }
  } else {
    const float* coords = (z == 0) ? cq : ck;
    u16* outp = (z == 0) ? qo : ko;
    const float postscale = (z == 0) ? QSCALE : 1.0f;
    const float invf = exp2f(-(float)fr * 0.83048202372184058f);
#pragma unroll
    for (int m = 0; m < 2; m++) {
      int rbase = row0 + wr * 32 + m * 16 + hi * 4;
#pragma unroll
      for (int np = 0; np < 3; np++) {
        int n1 = np * 2;
        int dd1 = n1 * 16 + fr;
#pragma unroll
        for (int r = 0; r < 4; r++) {
          int row = rbase + r;
          int b = row >> 11, l = row & (L - 1);
          float coord = coords[((size_t)(b * L + l)) * 3 + np];
          float ang = coord * invf;
          float sn = __sinf(ang), cs = __cosf(ang);
          float x1 = acc[m][n1][r], x2 = acc[m][n1 + 1][r];
          size_t base = ((size_t)((b * H + hh) * L + l)) * DH;
          outp[base + dd1] = f2bf((x1 * cs - x2 * sn) * postscale);
          outp[base + dd1 + 16] = f2bf((x1 * sn + x2 * cs) * postscale);
        }
      }
    }
  }
}

// ---------------------------------------------------------------------------
// Flash attention — r17 VERBATIM (measured 50.8us): 32x32x16 MFMA + k-split
// wave pairing, 256 thr (4 waves), reg-staged K (KSTR=104) + tau-perm'd V,
// defer-max, lane-local softmax, epilogue k-merge, XCD swizzle.
// ---------------------------------------------------------------------------
#define KSTR 104
#define VSTR 76
#define NT   (L / 64)
__global__ __launch_bounds__(256, 2)
void attn_fwd(const u16* __restrict__ q_ws, const u16* __restrict__ k_ws,
              const u16* __restrict__ vt_ws, u16* __restrict__ ao)
{
  __shared__ __attribute__((aligned(16))) u16 k_lds[2][64 * KSTR];
  __shared__ __attribute__((aligned(16))) u16 vt_lds[2][96 * VSTR];
  const int tid = threadIdx.x;
  const int lane = tid & 63;
  const int w = tid >> 6;

  const int f = blockIdx.x;
  const int xr = f & 7;
  const int g = f >> 3;          // 0..63
  const int qx = g & 31;
  const int bh = xr + 8 * (g >> 5);
  const int q0 = qx * 64;

  const int qlo = lane & 31;
  const int hi32 = lane >> 5;
  const int wq = w >> 1;
  const int kk0 = (w & 1) * 32;

  const u16* kbase = k_ws + (size_t)bh * L * DH;
  const u16* vtbase = vt_ws + (size_t)bh * DH * L;

  const int perm[4] = {0, 2, 1, 3};

  int kg_off[3], kl0[3], kl1[3];
  int vg_off[3], vl0[3], vl1[3];
#pragma unroll
  for (int it = 0; it < 3; it++) {
    int ch = tid + it * 256;              // 0..767
    int krow = ch / 12, dc = ch % 12;
    kg_off[it] = krow * DH + dc * 8;
    int c0 = dc * 2;
    kl0[it] = krow * KSTR + (c0 >> 2) * 16 + perm[c0 & 3] * 4;
    kl1[it] = krow * KSTR + (c0 >> 2) * 16 + perm[(c0 + 1) & 3] * 4;
    int vrow = ch >> 3, vq = (ch & 7) * 2;
    vg_off[it] = vrow * L + vq * 4;
    vl0[it] = vrow * VSTR + (vq >> 2) * 16 + perm[vq & 3] * 4;
    vl1[it] = vrow * VSTR + (vq >> 2) * 16 + perm[(vq + 1) & 3] * 4;
  }

  bf16x8 qf[6];
  {
    const u16* qb = q_ws + ((size_t)bh * L + q0 + wq * 32 + qlo) * DH;
#pragma unroll
    for (int s = 0; s < 6; s++) {
      bf16x4 a = *(const bf16x4*)(qb + s * 16 + hi32 * 4);
      bf16x4 b = *(const bf16x4*)(qb + s * 16 + hi32 * 4 + 8);
      bf16x8 q;
      q[0] = a[0]; q[1] = a[1]; q[2] = a[2]; q[3] = a[3];
      q[4] = b[0]; q[5] = b[1]; q[6] = b[2]; q[7] = b[3];
      qf[s] = q;
    }
  }

  f32x16 o[3] = {};
  float m_r = -1e30f, l_r = 0.f;

  u32x4 kreg[3], vreg[3];
  auto kissue = [&](int t) {
    const u16* kb = kbase + (size_t)t * 64 * DH;
    const u16* vb = vtbase + t * 64;
#pragma unroll
    for (int it = 0; it < 3; it++) {
      kreg[it] = *(const u32x4*)(kb + kg_off[it]);
      vreg[it] = *(const u32x4*)(vb + vg_off[it]);
    }
  };
  auto kwrite = [&](int bi) {
#pragma unroll
    for (int it = 0; it < 3; it++) {
      u32x2 klo = { kreg[it][0], kreg[it][1] };
      u32x2 khi = { kreg[it][2], kreg[it][3] };
      *(u32x2*)(&k_lds[bi][kl0[it]]) = klo;
      *(u32x2*)(&k_lds[bi][kl1[it]]) = khi;
      u32x2 vlo = { vreg[it][0], vreg[it][1] };
      u32x2 vhi = { vreg[it][2], vreg[it][3] };
      *(u32x2*)(&vt_lds[bi][vl0[it]]) = vlo;
      *(u32x2*)(&vt_lds[bi][vl1[it]]) = vhi;
    }
  };

  kissue(0);
  kwrite(0);
  __syncthreads();

  int cur = 0;
  for (int t = 0; t < NT; t++) {
    if (t + 1 < NT) kissue(t + 1);

    f32x16 s2 = {};
#pragma unroll
    for (int s = 0; s < 6; s++) {
      bf16x8 kfrag = *(const bf16x8*)(
          &k_lds[cur][(kk0 + qlo) * KSTR + s * 16 + hi32 * 8]);
      s2 = __builtin_amdgcn_mfma_f32_32x32x16_bf16(kfrag, qf[s], s2, 0, 0, 0);
    }

    float a0 = fmaxf(fmaxf(s2[0], s2[1]), s2[2]);
    float a1 = fmaxf(fmaxf(s2[3], s2[4]), s2[5]);
    float a2 = fmaxf(fmaxf(s2[6], s2[7]), s2[8]);
    float a3 = fmaxf(fmaxf(s2[9], s2[10]), s2[11]);
    float a4 = fmaxf(fmaxf(s2[12], s2[13]), s2[14]);
    float pmax = fmaxf(fmaxf(fmaxf(a0, a1), a2), fmaxf(fmaxf(a3, a4), s2[15]));
    if (!__all(pmax - m_r <= 8.0f)) {
      float mx = fmaxf(pmax, __shfl_xor(pmax, 32));
      float mn = fmaxf(m_r, mx);
      float alpha = exp2f(m_r - mn);
      m_r = mn;
      l_r *= alpha;
#pragma unroll
      for (int db = 0; db < 3; db++)
#pragma unroll
        for (int r = 0; r < 16; r++)
          o[db][r] *= alpha;
    }

    float p[16];
    float rs = 0.f;
#pragma unroll
    for (int r = 0; r < 16; r++) {
      p[r] = exp2f(s2[r] - m_r);
      rs += p[r];
    }
    l_r += rs;

    bf16x8 pt[2];
#pragma unroll
    for (int s = 0; s < 2; s++)
#pragma unroll
      for (int j = 0; j < 8; j++)
        pt[s][j] = (__bf16)p[s * 8 + j];

#pragma unroll
    for (int s = 0; s < 2; s++)
#pragma unroll
      for (int db = 0; db < 3; db++) {
        bf16x8 vfrag = *(const bf16x8*)(
            &vt_lds[cur][(db * 32 + qlo) * VSTR + kk0 + s * 16 + hi32 * 8]);
        o[db] = __builtin_amdgcn_mfma_f32_32x32x16_bf16(vfrag, pt[s], o[db], 0, 0, 0);
      }

    if (t + 1 < NT) {
      kwrite(cur ^ 1);
      __syncthreads();
      cur ^= 1;
    }
  }

  float l_w = l_r + __shfl_xor(l_r, 32);

  {
    float* xb = (float*)&k_lds[wq][0];
    const int base = lane * 52;
    if (w & 1) {
#pragma unroll
      for (int db = 0; db < 3; db++)
#pragma unroll
        for (int rg = 0; rg < 4; rg++) {
          f32x4 v = { o[db][rg * 4], o[db][rg * 4 + 1],
                      o[db][rg * 4 + 2], o[db][rg * 4 + 3] };
          *(f32x4*)&xb[base + db * 16 + rg * 4] = v;
        }
      xb[base + 48] = m_r;
      xb[base + 49] = l_w;
    }
    __syncthreads();
    if (!(w & 1)) {
      float m1 = xb[base + 48], l1 = xb[base + 49];
      float ms = fmaxf(m_r, m1);
      float c0 = exp2f(m_r - ms), c1 = exp2f(m1 - ms);
      float inv = 1.f / (l_w * c0 + l1 * c1);
      const int b = bh >> 3, hh = bh & 7;
      const int lrow = q0 + wq * 32 + qlo;
      u16* aop = ao + ((size_t)(b * L + lrow)) * D + hh * DH;
#pragma unroll
      for (int db = 0; db < 3; db++)
#pragma unroll
        for (int rg = 0; rg < 4; rg++) {
          f32x4 op = *(const f32x4*)&xb[base + db * 16 + rg * 4];
          u16x4 pk;
#pragma unroll
          for (int r4 = 0; r4 < 4; r4++)
            pk[r4] = f2bf((o[db][rg * 4 + r4] * c0 + op[r4] * c1) * inv);
          *(u16x4*)(aop + db * 32 + rg * 8 + hi32 * 4) = pk;
        }
    }
  }
}

// ---------------------------------------------------------------------------
// Output projection: out = AO @ Wo^T; 64x64 tiles, XCD swizzle, 2-deep
// prefetch + dbuf LDS; (256,3): 768 blocks = 3/CU one round.  (frozen)
// ---------------------------------------------------------------------------
__global__ __launch_bounds__(256, 3)
void gemm_out(const u16* __restrict__ A, const float* __restrict__ W,
              float* __restrict__ out)
{
  __shared__ u16 a_lds[2][64 * 40];
  __shared__ u16 b_lds[2][64 * 40];
  const int tid = threadIdx.x;
  const int lane = tid & 63;
  const int w = tid >> 6;
  const int wr = w >> 1, wc = w & 1;

  const int f = blockIdx.x;
  const int xr = f & 7;
  const int g = f >> 3;          // 0..95
  const int bx = g % 12;
  const int wq = g / 12;         // 0..7
  const int by = xr + 8 * wq;    // 0..63
  const int row0 = by * 64;
  const int col0 = bx * 64;

  f32x4 acc[2][2] = {};
  const int srow = tid >> 2;
  const int scol = (tid & 3) * 8;
  const u16* pA = A + (size_t)(row0 + srow) * D + scol;
  const float* pW = W + (size_t)(col0 + srow) * D + scol;
  const int fr = lane & 15;
  const int fk = (lane >> 4) * 8;

  auto issueG = [&](int k, u32x4* ra, f32x4* rb) {
    ra[0] = *(const u32x4*)(pA + k);
    rb[0] = *(const f32x4*)(pW + k);
    rb[1] = *(const f32x4*)(pW + k + 4);
  };
  auto writeG = [&](int bi, const u32x4* ra, const f32x4* rb) {
    *(u32x4*)(&a_lds[bi][srow * 40 + scol]) = ra[0];
    *(bf16x8*)(&b_lds[bi][srow * 40 + scol]) = cvt8r(rb[0], rb[1]);
  };
  auto computeG = [&](int bi) {
    bf16x8 af[2], bfr[2];
#pragma unroll
    for (int m = 0; m < 2; m++)
      af[m] = *(const bf16x8*)(&a_lds[bi][(wr * 32 + m * 16 + fr) * 40 + fk]);
#pragma unroll
    for (int n = 0; n < 2; n++)
      bfr[n] = *(const bf16x8*)(&b_lds[bi][(wc * 32 + n * 16 + fr) * 40 + fk]);
#pragma unroll
    for (int m = 0; m < 2; m++)
#pragma unroll
      for (int n = 0; n < 2; n++)
        acc[m][n] = __builtin_amdgcn_mfma_f32_16x16x32_bf16(af[m], bfr[n], acc[m][n], 0, 0, 0);
  };

  u32x4 raA[1], raB[1];
  f32x4 rbA[2], rbB[2];
  issueG(0, raB, rbB);
  writeG(0, raB, rbB);
  issueG(32, raA, rbA);
  __syncthreads();

  for (int k0 = 0; k0 < D; k0 += 64) {
    if (k0 + 64 < D) issueG(k0 + 64, raB, rbB);
    computeG(0);
    writeG(1, raA, rbA);
    __syncthreads();
    if (k0 + 96 < D) issueG(k0 + 96, raA, rbA);
    computeG(1);
    if (k0 + 64 < D) writeG(0, raB, rbB);
    __syncthreads();
  }

#pragma unroll
  for (int m = 0; m < 2; m++) {
    int rbase = row0 + wr * 32 + m * 16 + (lane >> 4) * 4;
#pragma unroll
    for (int n = 0; n < 2; n++) {
      int c = col0 + wc * 32 + n * 16 + fr;
#pragma unroll
      for (int r = 0; r < 4; r++)
        out[(size_t)(rbase + r) * D + c] = acc[m][n][r];
    }
  }
}

extern "C" void kernel_launch(void* const* d_in, const int* in_sizes, int n_in,
                              void* d_out, int out_size, void* d_ws, size_t ws_size,
                              hipStream_t stream) {
  (void)in_sizes; (void)n_in; (void)out_size;
  const float* Qin = (const float*)d_in[0];
  const float* Kin = (const float*)d_in[1];
  const float* Vin = (const float*)d_in[2];
  const float* cq  = (const float*)d_in[3];
  const float* ck  = (const float*)d_in[4];
  const float* Wq  = (const float*)d_in[5];
  const float* Wk  = (const float*)d_in[6];
  const float* Wv  = (const float*)d_in[7];
  const float* Wo  = (const float*)d_in[8];
  float* out = (float*)d_out;

  const size_t per = (size_t)NB * H * L * DH;  // 3,145,728 elems
  if (ws_size < 4 * per * sizeof(u16)) return;

  u16* q_ws  = (u16*)d_ws;
  u16* k_ws  = q_ws + per;
  u16* vt_ws = k_ws + per;
  u16* ao_ws = vt_ws + per;

  proj_qkv<<<dim3(768), dim3(256), 0, stream>>>(
      Qin, Kin, Vin, Wq, Wk, Wv, cq, ck, q_ws, k_ws, vt_ws);
  attn_fwd<<<dim3(32 * NB * H), dim3(256), 0, stream>>>(q_ws, k_ws, vt_ws, ao_ws);
  gemm_out<<<dim3(12 * 64), dim3(256), 0, stream>>>(ao_ws, Wo, out);
}